// Round 2
// baseline (723.456 us; speedup 1.0000x reference)
//
#include <hip/hip_runtime.h>
#include <cstdint>

#define B_ 64
#define M_ 1024
#define F_ 4
#define E_ 256
#define NW_ 32000
#define PL_ 128

// output element offsets (fp32 elements)
#define P_OFF   0
#define PV_OFF  65536
#define PR_OFF  2113536
#define H_OFF   2179072

typedef unsigned short u16;
typedef unsigned int u32;

typedef __bf16 bf16x8 __attribute__((ext_vector_type(8)));
typedef float f32x4 __attribute__((ext_vector_type(4)));

__device__ __forceinline__ u16 f2bf(float f) {
    u32 x = __builtin_bit_cast(u32, f);
    u32 r = (x + 0x7fffu + ((x >> 16) & 1u)) >> 16;
    return (u16)r;
}

__device__ __forceinline__ bf16x8 pack_bf8(float4 a, float4 b) {
    union { u16 s[8]; bf16x8 v; } u;
    u.s[0] = f2bf(a.x); u.s[1] = f2bf(a.y); u.s[2] = f2bf(a.z); u.s[3] = f2bf(a.w);
    u.s[4] = f2bf(b.x); u.s[5] = f2bf(b.y); u.s[6] = f2bf(b.z); u.s[7] = f2bf(b.w);
    return u.v;
}

// ---------------------------------------------------------------------------
// K1: GRU step + profile encoding.  64 blocks (one per b) x 256 threads.
// writes: q0 (fp32 ws), enc (fp32 ws), h -> out (fp32)
// ---------------------------------------------------------------------------
__global__ __launch_bounds__(256) void k_gru(
    const float* __restrict__ tables, const float* __restrict__ Wih,
    const float* __restrict__ Whh, const float* __restrict__ bih,
    const float* __restrict__ bhh, const float* __restrict__ Wp,
    const float* __restrict__ bp, const int* __restrict__ y,
    const float* __restrict__ h_, const float* __restrict__ pe,
    float* __restrict__ q0, float* __restrict__ enc, float* __restrict__ outh)
{
    int b = blockIdx.x, t = threadIdx.x;
    __shared__ float m_s[E_], h_s[E_], pe_s[PL_];
    int yb = y[b];
    float mv = 0.f;
    if (yb != 0) mv = tables[(size_t)NW_ * E_ + (size_t)yb * E_ + t]; // C[0] = tables[1]
    m_s[t] = mv;
    h_s[t] = h_[b * E_ + t];
    if (t < PL_) pe_s[t] = pe[b * PL_ + t];
    __syncthreads();

    float g_i[3], g_h[3];
#pragma unroll
    for (int g = 0; g < 3; g++) {
        int j = g * E_ + t;
        float ai = bih[j];
        float ah = bhh[j];
        const float4* wi = (const float4*)(Wih + (size_t)j * E_);
        const float4* wh = (const float4*)(Whh + (size_t)j * E_);
#pragma unroll 8
        for (int e = 0; e < E_ / 4; e++) {
            float4 a = wi[e], c = wh[e];
            ai += a.x * m_s[4 * e] + a.y * m_s[4 * e + 1] +
                  a.z * m_s[4 * e + 2] + a.w * m_s[4 * e + 3];
            ah += c.x * h_s[4 * e] + c.y * h_s[4 * e + 1] +
                  c.z * h_s[4 * e + 2] + c.w * h_s[4 * e + 3];
        }
        g_i[g] = ai; g_h[g] = ah;
    }
    float r = 1.f / (1.f + expf(-(g_i[0] + g_h[0])));
    float z = 1.f / (1.f + expf(-(g_i[1] + g_h[1])));
    float n = tanhf(g_i[2] + r * g_h[2]);
    float hv = (1.f - z) * n + z * h_s[t];
    q0[b * E_ + t] = hv;
    outh[H_OFF - H_OFF + b * E_ + t] = hv;   // outh already offset by caller

    // enc[b,e] = bp[e] + sum_p pe[b,p] * Wp[e,p]
    float ea = bp[t];
    const float4* wp = (const float4*)(Wp + (size_t)t * PL_);
#pragma unroll 8
    for (int p = 0; p < PL_ / 4; p++) {
        float4 a = wp[p];
        ea += a.x * pe_s[4 * p] + a.y * pe_s[4 * p + 1] +
              a.z * pe_s[4 * p + 2] + a.w * pe_s[4 * p + 3];
    }
    enc[b * E_ + t] = ea;
}

// ---------------------------------------------------------------------------
// K2: attention scores p[b,m] = sum_f sum_e tab[idx_f][e] * q[b,e]
// MODE 0: write p_ws fp32.  MODE 1: also p_resto -> out fp32.
// MODE 2: final hop, write p -> out fp32 only.
// grid (16, 64), block 256 (4 waves x 16 m each; lanes over e, 4 elems/lane)
// ---------------------------------------------------------------------------
template <int MODE>
__global__ __launch_bounds__(256) void k_scores(
    const float* __restrict__ tab, const int* __restrict__ ctx,
    const float* __restrict__ q, const float* __restrict__ enc,
    float* __restrict__ p_ws, float* __restrict__ out)
{
    int b = blockIdx.y, grp = blockIdx.x;
    int lane = threadIdx.x & 63, w = threadIdx.x >> 6;
    int e0 = lane * 4;
    const float4 qv = *(const float4*)(q + b * E_ + e0);
    float4 qe = make_float4(0.f, 0.f, 0.f, 0.f);
    if (MODE == 1) {
        const float4 ev = *(const float4*)(enc + b * E_ + e0);
        qe = make_float4(qv.x * ev.x, qv.y * ev.y, qv.z * ev.z, qv.w * ev.w);
    }
    for (int i = 0; i < 16; i++) {
        int m = grp * 64 + w * 16 + i;
        const int4 ci = *(const int4*)(ctx + ((size_t)b * M_ + m) * 4);
        float acc = 0.f, racc = 0.f;
        int idx4[4] = {ci.x, ci.y, ci.z, ci.w};
#pragma unroll
        for (int f = 0; f < 4; f++) {
            int idx = idx4[f];
            if (idx != 0) {  // wave-uniform branch (all lanes read same ctx row)
                const float4 t4 = *(const float4*)(tab + (size_t)idx * E_ + e0);
                acc += t4.x * qv.x + t4.y * qv.y + t4.z * qv.z + t4.w * qv.w;
                if (MODE == 1)
                    racc += t4.x * qe.x + t4.y * qe.y + t4.z * qe.z + t4.w * qe.w;
            }
        }
#pragma unroll
        for (int o = 32; o > 0; o >>= 1) {
            acc += __shfl_xor(acc, o, 64);
            if (MODE == 1) racc += __shfl_xor(racc, o, 64);
        }
        if (lane == 0) {
            if (MODE == 2) out[P_OFF + (size_t)b * M_ + m] = acc;
            else           p_ws[(size_t)b * M_ + m] = acc;
            if (MODE == 1) out[PR_OFF + (size_t)b * M_ + m] = racc;
        }
    }
}

// ---------------------------------------------------------------------------
// K3a: softmax over m (in-place in p_ws) + qnext = qcur.  64 blocks x 256.
// ---------------------------------------------------------------------------
__global__ __launch_bounds__(256) void k_soft(
    float* __restrict__ p_ws, const float* __restrict__ qcur,
    float* __restrict__ qnext)
{
    int b = blockIdx.x, t = threadIdx.x;
    __shared__ float red[256];
    float4 v = *(const float4*)(p_ws + (size_t)b * M_ + t * 4);
    float lm = fmaxf(fmaxf(v.x, v.y), fmaxf(v.z, v.w));
    red[t] = lm;
    __syncthreads();
    for (int s = 128; s > 0; s >>= 1) {
        if (t < s) red[t] = fmaxf(red[t], red[t + s]);
        __syncthreads();
    }
    float mx = red[0];
    __syncthreads();
    float e0 = expf(v.x - mx), e1 = expf(v.y - mx);
    float e2 = expf(v.z - mx), e3 = expf(v.w - mx);
    red[t] = e0 + e1 + e2 + e3;
    __syncthreads();
    for (int s = 128; s > 0; s >>= 1) {
        if (t < s) red[t] += red[t + s];
        __syncthreads();
    }
    float inv = 1.f / red[0];
    float4 o = make_float4(e0 * inv, e1 * inv, e2 * inv, e3 * inv);
    *(float4*)(p_ws + (size_t)b * M_ + t * 4) = o;
    qnext[b * E_ + t] = qcur[b * E_ + t];
}

// ---------------------------------------------------------------------------
// K3b: o[b,e] partial = sum_{m chunk} attn[b,m] * sum_f tabC[idx][e];
// atomicAdd into qnext.  grid (8, 64), block 256 (thread -> e).
// ---------------------------------------------------------------------------
__global__ __launch_bounds__(256) void k_opart(
    const float* __restrict__ tabC, const int* __restrict__ ctx,
    const float* __restrict__ attn, float* __restrict__ qnext)
{
    int b = blockIdx.y, ch = blockIdx.x, t = threadIdx.x;
    __shared__ float w_s[128];
    __shared__ int4 c_s[128];
    int m0 = ch * 128;
    if (t < 128) {
        w_s[t] = attn[(size_t)b * M_ + m0 + t];
    } else {
        int i = t - 128;
        c_s[i] = *(const int4*)(ctx + ((size_t)b * M_ + m0 + i) * 4);
    }
    __syncthreads();
    float acc = 0.f;
    for (int i = 0; i < 128; i++) {
        float wgt = w_s[i];
        int4 ci = c_s[i];
        if (ci.x) acc += wgt * tabC[(size_t)ci.x * E_ + t];
        if (ci.y) acc += wgt * tabC[(size_t)ci.y * E_ + t];
        if (ci.z) acc += wgt * tabC[(size_t)ci.z * E_ + t];
        if (ci.w) acc += wgt * tabC[(size_t)ci.w * E_ + t];
    }
    atomicAdd(&qnext[b * E_ + t], acc);
}

// ---------------------------------------------------------------------------
// K4: p_vocab[b,v] = [h ; o0] . Wv[v,:] + bv[v]  via MFMA 16x16x32 bf16
// (inputs cast fp32->bf16 in-flight; rel err ~0.4% << 2% threshold).
// X = [q0, q1-q0] (64x512 -> bf16) staged to LDS (xor-swizzled 16B chunks).
// grid 250 blocks (128 n each), block 256 (4 waves; wave = 64m x 32n).
// ---------------------------------------------------------------------------
__global__ __launch_bounds__(256) void k_pvocab(
    const float* __restrict__ Wv, const float* __restrict__ bv,
    const float* __restrict__ q0, const float* __restrict__ q1,
    float* __restrict__ out)
{
    __shared__ u16 X[64 * 512];  // 64KB
    int t = threadIdx.x;
#pragma unroll
    for (int it = 0; it < 16; it++) {
        int id = t + it * 256;
        int bb = id >> 6, c = id & 63;  // chunk c: 8 bf16 = 16B
        float v[8];
        if (c < 32) {
            const float* s = q0 + bb * E_ + c * 8;
#pragma unroll
            for (int j = 0; j < 8; j++) v[j] = s[j];
        } else {
            const float* s1 = q1 + bb * E_ + (c - 32) * 8;
            const float* s0 = q0 + bb * E_ + (c - 32) * 8;
#pragma unroll
            for (int j = 0; j < 8; j++) v[j] = s1[j] - s0[j];
        }
        u32 ww[4];
#pragma unroll
        for (int j = 0; j < 4; j++)
            ww[j] = (u32)f2bf(v[2 * j]) | ((u32)f2bf(v[2 * j + 1]) << 16);
        uint4 uv = make_uint4(ww[0], ww[1], ww[2], ww[3]);
        *(uint4*)(&X[bb * 512 + ((c ^ (bb & 7)) << 3)]) = uv;
    }
    __syncthreads();

    int lane = t & 63, w = t >> 6;
    int n0 = blockIdx.x * 128 + w * 32;
    int l15 = lane & 15, quad = lane >> 4;
    f32x4 acc[4][2];
#pragma unroll
    for (int mt = 0; mt < 4; mt++)
#pragma unroll
        for (int nt = 0; nt < 2; nt++)
            acc[mt][nt] = f32x4{0.f, 0.f, 0.f, 0.f};

    for (int ks = 0; ks < 16; ks++) {
        bf16x8 a[4], bfr[2];
#pragma unroll
        for (int mt = 0; mt < 4; mt++) {
            int m = mt * 16 + l15;
            int c = ks * 4 + quad;
            a[mt] = *(const bf16x8*)(&X[m * 512 + ((c ^ (m & 7)) << 3)]);
        }
#pragma unroll
        for (int nt = 0; nt < 2; nt++) {
            int n = n0 + nt * 16 + l15;
            const float4* wp = (const float4*)(Wv + (size_t)n * 512 + ks * 32 + quad * 8);
            bfr[nt] = pack_bf8(wp[0], wp[1]);
        }
#pragma unroll
        for (int mt = 0; mt < 4; mt++)
#pragma unroll
            for (int nt = 0; nt < 2; nt++)
                acc[mt][nt] = __builtin_amdgcn_mfma_f32_16x16x32_bf16(
                    a[mt], bfr[nt], acc[mt][nt], 0, 0, 0);
    }
#pragma unroll
    for (int nt = 0; nt < 2; nt++) {
        int n = n0 + nt * 16 + l15;
        float bvv = bv[n];
#pragma unroll
        for (int mt = 0; mt < 4; mt++) {
#pragma unroll
            for (int j = 0; j < 4; j++) {
                int m = mt * 16 + quad * 4 + j;
                out[PV_OFF + (size_t)m * 32000 + n] = acc[mt][nt][j] + bvv;
            }
        }
    }
}

// ---------------------------------------------------------------------------
extern "C" void kernel_launch(void* const* d_in, const int* in_sizes, int n_in,
                              void* d_out, int out_size, void* d_ws, size_t ws_size,
                              hipStream_t stream)
{
    const float* tables = (const float*)d_in[0];
    const float* Wih = (const float*)d_in[1];
    const float* Whh = (const float*)d_in[2];
    const float* bih = (const float*)d_in[3];
    const float* bhh = (const float*)d_in[4];
    const float* Wp  = (const float*)d_in[5];
    const float* bp  = (const float*)d_in[6];
    const float* Wv  = (const float*)d_in[7];
    const float* bv  = (const float*)d_in[8];
    const int* ctx = (const int*)d_in[9];
    const int* y   = (const int*)d_in[10];
    const float* h_  = (const float*)d_in[11];
    const float* pe  = (const float*)d_in[12];
    float* out = (float*)d_out;

    float* Wf   = (float*)d_ws;
    float* q    = Wf;           // q[hop] at hop*16384, hops 0..2 (49152 floats)
    float* enc  = Wf + 65536;   // 16384 floats
    float* p_ws = Wf + 81920;   // 65536 floats (scores, then attn in-place)

    const size_t TSZ = (size_t)NW_ * E_;

    k_gru<<<64, 256, 0, stream>>>(tables, Wih, Whh, bih, bhh, Wp, bp, y, h_, pe,
                                  q, enc, out + H_OFF);
    // hop 0: scores vs tables[0], o vs tables[1]
    k_scores<0><<<dim3(16, 64), 256, 0, stream>>>(tables, ctx, q, enc, p_ws, out);
    k_soft<<<64, 256, 0, stream>>>(p_ws, q, q + 16384);
    k_opart<<<dim3(8, 64), 256, 0, stream>>>(tables + TSZ, ctx, p_ws, q + 16384);
    // hop 1: scores vs tables[1] (+ p_resto), o vs tables[2]
    k_scores<1><<<dim3(16, 64), 256, 0, stream>>>(tables + TSZ, ctx, q + 16384,
                                                  enc, p_ws, out);
    k_soft<<<64, 256, 0, stream>>>(p_ws, q + 16384, q + 32768);
    k_opart<<<dim3(8, 64), 256, 0, stream>>>(tables + 2 * TSZ, ctx, p_ws, q + 32768);
    // hop 2: final scores -> p output (no softmax / o needed)
    k_scores<2><<<dim3(16, 64), 256, 0, stream>>>(tables + 2 * TSZ, ctx, q + 32768,
                                                  enc, p_ws, out);
    // p_vocab head
    k_pvocab<<<250, 256, 0, stream>>>(Wv, bv, q, q + 16384, out);
}

// Round 3
// 458.438 us; speedup vs baseline: 1.5781x; 1.5781x over previous
//
#include <hip/hip_runtime.h>
#include <cstdint>

#define B_ 64
#define M_ 1024
#define F_ 4
#define E_ 256
#define NW_ 32000
#define PL_ 128

// output element offsets (fp32 elements)
#define P_OFF   0
#define PV_OFF  65536
#define PR_OFF  2113536
#define H_OFF   2179072

typedef unsigned short u16;
typedef unsigned int u32;

typedef __bf16 bf16x8 __attribute__((ext_vector_type(8)));
typedef float f32x4 __attribute__((ext_vector_type(4)));

__device__ __forceinline__ u16 f2bf(float f) {
    u32 x = __builtin_bit_cast(u32, f);
    u32 r = (x + 0x7fffu + ((x >> 16) & 1u)) >> 16;
    return (u16)r;
}

__device__ __forceinline__ bf16x8 pack_bf8(float4 a, float4 b) {
    union { u16 s[8]; bf16x8 v; } u;
    u.s[0] = f2bf(a.x); u.s[1] = f2bf(a.y); u.s[2] = f2bf(a.z); u.s[3] = f2bf(a.w);
    u.s[4] = f2bf(b.x); u.s[5] = f2bf(b.y); u.s[6] = f2bf(b.z); u.s[7] = f2bf(b.w);
    return u.v;
}

// ---------------------------------------------------------------------------
// K1: GRU step + profile encoding.  64 blocks (one per b) x 256 threads.
// ---------------------------------------------------------------------------
__global__ __launch_bounds__(256) void k_gru(
    const float* __restrict__ tables, const float* __restrict__ Wih,
    const float* __restrict__ Whh, const float* __restrict__ bih,
    const float* __restrict__ bhh, const float* __restrict__ Wp,
    const float* __restrict__ bp, const int* __restrict__ y,
    const float* __restrict__ h_, const float* __restrict__ pe,
    float* __restrict__ q0, float* __restrict__ enc, float* __restrict__ outh)
{
    int b = blockIdx.x, t = threadIdx.x;
    __shared__ float m_s[E_], h_s[E_], pe_s[PL_];
    int yb = y[b];
    // tables[1] row 0 is all-zero, so no idx==0 branch needed
    m_s[t] = tables[(size_t)NW_ * E_ + (size_t)yb * E_ + t];
    h_s[t] = h_[b * E_ + t];
    if (t < PL_) pe_s[t] = pe[b * PL_ + t];
    __syncthreads();

    float g_i[3], g_h[3];
#pragma unroll
    for (int g = 0; g < 3; g++) {
        int j = g * E_ + t;
        float ai = bih[j];
        float ah = bhh[j];
        const float4* wi = (const float4*)(Wih + (size_t)j * E_);
        const float4* wh = (const float4*)(Whh + (size_t)j * E_);
#pragma unroll 8
        for (int e = 0; e < E_ / 4; e++) {
            float4 a = wi[e], c = wh[e];
            ai += a.x * m_s[4 * e] + a.y * m_s[4 * e + 1] +
                  a.z * m_s[4 * e + 2] + a.w * m_s[4 * e + 3];
            ah += c.x * h_s[4 * e] + c.y * h_s[4 * e + 1] +
                  c.z * h_s[4 * e + 2] + c.w * h_s[4 * e + 3];
        }
        g_i[g] = ai; g_h[g] = ah;
    }
    float r = 1.f / (1.f + expf(-(g_i[0] + g_h[0])));
    float z = 1.f / (1.f + expf(-(g_i[1] + g_h[1])));
    float n = tanhf(g_i[2] + r * g_h[2]);
    float hv = (1.f - z) * n + z * h_s[t];
    q0[b * E_ + t] = hv;
    outh[b * E_ + t] = hv;

    float ea = bp[t];
    const float4* wp = (const float4*)(Wp + (size_t)t * PL_);
#pragma unroll 8
    for (int p = 0; p < PL_ / 4; p++) {
        float4 a = wp[p];
        ea += a.x * pe_s[4 * p] + a.y * pe_s[4 * p + 1] +
              a.z * pe_s[4 * p + 2] + a.w * pe_s[4 * p + 3];
    }
    enc[b * E_ + t] = ea;
}

// ---------------------------------------------------------------------------
// K2: attention scores p[b,m] = sum_f sum_e tab[idx_f][e] * q[b,e]
// MODE 0: write p_ws.  MODE 1: also p_resto -> out.  MODE 2: p -> out only.
// grid (32, 64), block 256: 4 waves x 8 m each; lane -> 4 e's (float4).
// All 32 row-gathers of a wave are independent (ctx prefetched) -> deep MLP.
// Table row 0 is all-zero, so idx==0 needs no masking.
// ---------------------------------------------------------------------------
template <int MODE>
__global__ __launch_bounds__(256) void k_scores(
    const float* __restrict__ tab, const int* __restrict__ ctx,
    const float* __restrict__ q, const float* __restrict__ enc,
    float* __restrict__ p_ws, float* __restrict__ out)
{
    int b = blockIdx.y, grp = blockIdx.x;
    int lane = threadIdx.x & 63, w = threadIdx.x >> 6;
    int e0 = lane * 4;
    const float4 qv = *(const float4*)(q + b * E_ + e0);
    float4 qe = make_float4(0.f, 0.f, 0.f, 0.f);
    if (MODE == 1) {
        const float4 ev = *(const float4*)(enc + b * E_ + e0);
        qe = make_float4(qv.x * ev.x, qv.y * ev.y, qv.z * ev.z, qv.w * ev.w);
    }
    int mbase = grp * 32 + w * 8;
    const int4* cp = (const int4*)(ctx + ((size_t)b * M_ + mbase) * 4);
    int4 c[8];
#pragma unroll
    for (int i = 0; i < 8; i++) c[i] = cp[i];

    float pa[8], pr[8];
#pragma unroll
    for (int i = 0; i < 8; i++) {
        const float4 t0 = *(const float4*)(tab + (size_t)c[i].x * E_ + e0);
        const float4 t1 = *(const float4*)(tab + (size_t)c[i].y * E_ + e0);
        const float4 t2 = *(const float4*)(tab + (size_t)c[i].z * E_ + e0);
        const float4 t3 = *(const float4*)(tab + (size_t)c[i].w * E_ + e0);
        float rx = t0.x + t1.x + t2.x + t3.x;
        float ry = t0.y + t1.y + t2.y + t3.y;
        float rz = t0.z + t1.z + t2.z + t3.z;
        float rw = t0.w + t1.w + t2.w + t3.w;
        pa[i] = rx * qv.x + ry * qv.y + rz * qv.z + rw * qv.w;
        if (MODE == 1) pr[i] = rx * qe.x + ry * qe.y + rz * qe.z + rw * qe.w;
    }
#pragma unroll
    for (int o = 32; o > 0; o >>= 1) {
#pragma unroll
        for (int i = 0; i < 8; i++) {
            pa[i] += __shfl_xor(pa[i], o, 64);
            if (MODE == 1) pr[i] += __shfl_xor(pr[i], o, 64);
        }
    }
    if (lane == 0) {
#pragma unroll
        for (int i = 0; i < 8; i++) {
            if (MODE == 2) out[P_OFF + (size_t)b * M_ + mbase + i] = pa[i];
            else           p_ws[(size_t)b * M_ + mbase + i] = pa[i];
            if (MODE == 1) out[PR_OFF + (size_t)b * M_ + mbase + i] = pr[i];
        }
    }
}

// ---------------------------------------------------------------------------
// K3a: softmax over m (in-place in p_ws) + qnext = qcur.  64 blocks x 256.
// ---------------------------------------------------------------------------
__global__ __launch_bounds__(256) void k_soft(
    float* __restrict__ p_ws, const float* __restrict__ qcur,
    float* __restrict__ qnext)
{
    int b = blockIdx.x, t = threadIdx.x;
    __shared__ float red[256];
    float4 v = *(const float4*)(p_ws + (size_t)b * M_ + t * 4);
    float lm = fmaxf(fmaxf(v.x, v.y), fmaxf(v.z, v.w));
    red[t] = lm;
    __syncthreads();
    for (int s = 128; s > 0; s >>= 1) {
        if (t < s) red[t] = fmaxf(red[t], red[t + s]);
        __syncthreads();
    }
    float mx = red[0];
    __syncthreads();
    float e0 = expf(v.x - mx), e1 = expf(v.y - mx);
    float e2 = expf(v.z - mx), e3 = expf(v.w - mx);
    red[t] = e0 + e1 + e2 + e3;
    __syncthreads();
    for (int s = 128; s > 0; s >>= 1) {
        if (t < s) red[t] += red[t + s];
        __syncthreads();
    }
    float inv = 1.f / red[0];
    float4 o = make_float4(e0 * inv, e1 * inv, e2 * inv, e3 * inv);
    *(float4*)(p_ws + (size_t)b * M_ + t * 4) = o;
    qnext[b * E_ + t] = qcur[b * E_ + t];
}

// ---------------------------------------------------------------------------
// K3b: o[b,e] += sum_m attn[b,m] * sum_f tabC[idx][e], atomic into qnext.
// grid (32, 64), block 256: 4 waves x 8 m each; lane -> float4 of e.
// LDS cross-wave reduce -> 1 atomicAdd per element per block.
// ---------------------------------------------------------------------------
__global__ __launch_bounds__(256) void k_opart(
    const float* __restrict__ tabC, const int* __restrict__ ctx,
    const float* __restrict__ attn, float* __restrict__ qnext)
{
    int b = blockIdx.y, ch = blockIdx.x;
    int lane = threadIdx.x & 63, w = threadIdx.x >> 6;
    int e0 = lane * 4;
    int mbase = ch * 32 + w * 8;

    const int4* cp = (const int4*)(ctx + ((size_t)b * M_ + mbase) * 4);
    int4 c[8];
#pragma unroll
    for (int i = 0; i < 8; i++) c[i] = cp[i];
    const float4* ap = (const float4*)(attn + (size_t)b * M_ + mbase);
    float4 a01 = ap[0], a23 = ap[1];
    float wg[8] = {a01.x, a01.y, a01.z, a01.w, a23.x, a23.y, a23.z, a23.w};

    float4 acc0 = make_float4(0.f, 0.f, 0.f, 0.f);
    float4 acc1 = make_float4(0.f, 0.f, 0.f, 0.f);
#pragma unroll
    for (int i = 0; i < 8; i += 2) {
        const float4 t0 = *(const float4*)(tabC + (size_t)c[i].x * E_ + e0);
        const float4 t1 = *(const float4*)(tabC + (size_t)c[i].y * E_ + e0);
        const float4 t2 = *(const float4*)(tabC + (size_t)c[i].z * E_ + e0);
        const float4 t3 = *(const float4*)(tabC + (size_t)c[i].w * E_ + e0);
        const float4 u0 = *(const float4*)(tabC + (size_t)c[i + 1].x * E_ + e0);
        const float4 u1 = *(const float4*)(tabC + (size_t)c[i + 1].y * E_ + e0);
        const float4 u2 = *(const float4*)(tabC + (size_t)c[i + 1].z * E_ + e0);
        const float4 u3 = *(const float4*)(tabC + (size_t)c[i + 1].w * E_ + e0);
        float w0 = wg[i], w1 = wg[i + 1];
        acc0.x += w0 * (t0.x + t1.x + t2.x + t3.x);
        acc0.y += w0 * (t0.y + t1.y + t2.y + t3.y);
        acc0.z += w0 * (t0.z + t1.z + t2.z + t3.z);
        acc0.w += w0 * (t0.w + t1.w + t2.w + t3.w);
        acc1.x += w1 * (u0.x + u1.x + u2.x + u3.x);
        acc1.y += w1 * (u0.y + u1.y + u2.y + u3.y);
        acc1.z += w1 * (u0.z + u1.z + u2.z + u3.z);
        acc1.w += w1 * (u0.w + u1.w + u2.w + u3.w);
    }
    float4 acc = make_float4(acc0.x + acc1.x, acc0.y + acc1.y,
                             acc0.z + acc1.z, acc0.w + acc1.w);
    __shared__ float red[4][E_];
    *(float4*)&red[w][e0] = acc;
    __syncthreads();
    int t = threadIdx.x;
    float s = red[0][t] + red[1][t] + red[2][t] + red[3][t];
    atomicAdd(qnext + b * E_ + t, s);
}

// ---------------------------------------------------------------------------
// K4: p_vocab = [h ; o0] @ Wv^T + bv via MFMA 16x16x32 bf16.
// ---------------------------------------------------------------------------
__global__ __launch_bounds__(256) void k_pvocab(
    const float* __restrict__ Wv, const float* __restrict__ bv,
    const float* __restrict__ q0, const float* __restrict__ q1,
    float* __restrict__ out)
{
    __shared__ u16 X[64 * 512];  // 64KB
    int t = threadIdx.x;
#pragma unroll
    for (int it = 0; it < 16; it++) {
        int id = t + it * 256;
        int bb = id >> 6, c = id & 63;  // chunk c: 8 bf16 = 16B
        float v[8];
        if (c < 32) {
            const float* s = q0 + bb * E_ + c * 8;
#pragma unroll
            for (int j = 0; j < 8; j++) v[j] = s[j];
        } else {
            const float* s1 = q1 + bb * E_ + (c - 32) * 8;
            const float* s0 = q0 + bb * E_ + (c - 32) * 8;
#pragma unroll
            for (int j = 0; j < 8; j++) v[j] = s1[j] - s0[j];
        }
        u32 ww[4];
#pragma unroll
        for (int j = 0; j < 4; j++)
            ww[j] = (u32)f2bf(v[2 * j]) | ((u32)f2bf(v[2 * j + 1]) << 16);
        uint4 uv = make_uint4(ww[0], ww[1], ww[2], ww[3]);
        *(uint4*)(&X[bb * 512 + ((c ^ (bb & 7)) << 3)]) = uv;
    }
    __syncthreads();

    int lane = t & 63, w = t >> 6;
    int n0 = blockIdx.x * 128 + w * 32;
    int l15 = lane & 15, quad = lane >> 4;
    f32x4 acc[4][2];
#pragma unroll
    for (int mt = 0; mt < 4; mt++)
#pragma unroll
        for (int nt = 0; nt < 2; nt++)
            acc[mt][nt] = f32x4{0.f, 0.f, 0.f, 0.f};

    for (int ks = 0; ks < 16; ks++) {
        bf16x8 a[4], bfr[2];
#pragma unroll
        for (int mt = 0; mt < 4; mt++) {
            int m = mt * 16 + l15;
            int c = ks * 4 + quad;
            a[mt] = *(const bf16x8*)(&X[m * 512 + ((c ^ (m & 7)) << 3)]);
        }
#pragma unroll
        for (int nt = 0; nt < 2; nt++) {
            int n = n0 + nt * 16 + l15;
            const float4* wp = (const float4*)(Wv + (size_t)n * 512 + ks * 32 + quad * 8);
            bfr[nt] = pack_bf8(wp[0], wp[1]);
        }
#pragma unroll
        for (int mt = 0; mt < 4; mt++)
#pragma unroll
            for (int nt = 0; nt < 2; nt++)
                acc[mt][nt] = __builtin_amdgcn_mfma_f32_16x16x32_bf16(
                    a[mt], bfr[nt], acc[mt][nt], 0, 0, 0);
    }
#pragma unroll
    for (int nt = 0; nt < 2; nt++) {
        int n = n0 + nt * 16 + l15;
        float bvv = bv[n];
#pragma unroll
        for (int mt = 0; mt < 4; mt++) {
#pragma unroll
            for (int j = 0; j < 4; j++) {
                int m = mt * 16 + quad * 4 + j;
                out[PV_OFF + (size_t)m * 32000 + n] = acc[mt][nt][j] + bvv;
            }
        }
    }
}

// ---------------------------------------------------------------------------
extern "C" void kernel_launch(void* const* d_in, const int* in_sizes, int n_in,
                              void* d_out, int out_size, void* d_ws, size_t ws_size,
                              hipStream_t stream)
{
    const float* tables = (const float*)d_in[0];
    const float* Wih = (const float*)d_in[1];
    const float* Whh = (const float*)d_in[2];
    const float* bih = (const float*)d_in[3];
    const float* bhh = (const float*)d_in[4];
    const float* Wp  = (const float*)d_in[5];
    const float* bp  = (const float*)d_in[6];
    const float* Wv  = (const float*)d_in[7];
    const float* bv  = (const float*)d_in[8];
    const int* ctx = (const int*)d_in[9];
    const int* y   = (const int*)d_in[10];
    const float* h_  = (const float*)d_in[11];
    const float* pe  = (const float*)d_in[12];
    float* out = (float*)d_out;

    float* Wf   = (float*)d_ws;
    float* q    = Wf;           // q[hop] at hop*16384, hops 0..2
    float* enc  = Wf + 65536;
    float* p_ws = Wf + 81920;   // scores, then attn in-place

    const size_t TSZ = (size_t)NW_ * E_;

    k_gru<<<64, 256, 0, stream>>>(tables, Wih, Whh, bih, bhh, Wp, bp, y, h_, pe,
                                  q, enc, out + H_OFF);
    // hop 0
    k_scores<0><<<dim3(32, 64), 256, 0, stream>>>(tables, ctx, q, enc, p_ws, out);
    k_soft<<<64, 256, 0, stream>>>(p_ws, q, q + 16384);
    k_opart<<<dim3(32, 64), 256, 0, stream>>>(tables + TSZ, ctx, p_ws, q + 16384);
    // hop 1 (+ p_resto)
    k_scores<1><<<dim3(32, 64), 256, 0, stream>>>(tables + TSZ, ctx, q + 16384,
                                                  enc, p_ws, out);
    k_soft<<<64, 256, 0, stream>>>(p_ws, q + 16384, q + 32768);
    k_opart<<<dim3(32, 64), 256, 0, stream>>>(tables + 2 * TSZ, ctx, p_ws, q + 32768);
    // hop 2: final scores -> p output
    k_scores<2><<<dim3(32, 64), 256, 0, stream>>>(tables + 2 * TSZ, ctx, q + 32768,
                                                  enc, p_ws, out);
    // p_vocab head
    k_pvocab<<<250, 256, 0, stream>>>(Wv, bv, q, q + 16384, out);
}

// Round 4
// 399.290 us; speedup vs baseline: 1.8119x; 1.1481x over previous
//
#include <hip/hip_runtime.h>
#include <cstdint>

#define B_ 64
#define M_ 1024
#define F_ 4
#define E_ 256
#define NW_ 32000
#define PL_ 128

// output element offsets (fp32 elements)
#define P_OFF   0
#define PV_OFF  65536
#define PR_OFF  2113536
#define H_OFF   2179072

typedef unsigned short u16;
typedef unsigned int u32;

typedef __bf16 bf16x8 __attribute__((ext_vector_type(8)));
typedef float f32x4 __attribute__((ext_vector_type(4)));

__device__ __forceinline__ u16 f2bf(float f) {
    u32 x = __builtin_bit_cast(u32, f);
    u32 r = (x + 0x7fffu + ((x >> 16) & 1u)) >> 16;
    return (u16)r;
}
__device__ __forceinline__ float bflo(u32 v) {
    return __builtin_bit_cast(float, v << 16);
}
__device__ __forceinline__ float bfhi(u32 v) {
    return __builtin_bit_cast(float, v & 0xffff0000u);
}
// dot of 8 packed bf16 (uint4) with 8 fp32 (two float4)
__device__ __forceinline__ float dot8(uint4 u, float4 qa, float4 qb) {
    return bflo(u.x) * qa.x + bfhi(u.x) * qa.y + bflo(u.y) * qa.z + bfhi(u.y) * qa.w +
           bflo(u.z) * qb.x + bfhi(u.z) * qb.y + bflo(u.w) * qb.z + bfhi(u.w) * qb.w;
}
__device__ __forceinline__ void acc8(uint4 u, float* a) {
    a[0] += bflo(u.x); a[1] += bfhi(u.x); a[2] += bflo(u.y); a[3] += bfhi(u.y);
    a[4] += bflo(u.z); a[5] += bfhi(u.z); a[6] += bflo(u.w); a[7] += bfhi(u.w);
}
__device__ __forceinline__ uint4 pack8(const float* s) {
    uint4 u;
    u.x = (u32)f2bf(s[0]) | ((u32)f2bf(s[1]) << 16);
    u.y = (u32)f2bf(s[2]) | ((u32)f2bf(s[3]) << 16);
    u.z = (u32)f2bf(s[4]) | ((u32)f2bf(s[5]) << 16);
    u.w = (u32)f2bf(s[6]) | ((u32)f2bf(s[7]) << 16);
    return u;
}
__device__ __forceinline__ bf16x8 pack_bf8(float4 a, float4 b) {
    union { u16 s[8]; bf16x8 v; } u;
    u.s[0] = f2bf(a.x); u.s[1] = f2bf(a.y); u.s[2] = f2bf(a.z); u.s[3] = f2bf(a.w);
    u.s[4] = f2bf(b.x); u.s[5] = f2bf(b.y); u.s[6] = f2bf(b.z); u.s[7] = f2bf(b.w);
    return u.v;
}

// ---------------------------------------------------------------------------
// K0: convert tables 0..2 (fp32) -> bf16: t0b[idx][256], t12[idx][2][256]
// grid (4000, 3) x 256; thread handles 8 consecutive floats.
// ---------------------------------------------------------------------------
__global__ __launch_bounds__(256) void k_conv(
    const float* __restrict__ tables, u16* __restrict__ t0b, u16* __restrict__ t12)
{
    int t = blockIdx.y;
    int c = blockIdx.x * 256 + threadIdx.x;         // chunk of 8 floats
    const float* src = tables + (size_t)t * NW_ * E_ + (size_t)c * 8;
    float4 a = *(const float4*)src;
    float4 b = *(const float4*)(src + 4);
    float s[8] = {a.x, a.y, a.z, a.w, b.x, b.y, b.z, b.w};
    uint4 u = pack8(s);
    if (t == 0) {
        *(uint4*)(t0b + (size_t)c * 8) = u;
    } else {
        int row = c >> 5, e = (c & 31) * 8;
        *(uint4*)(t12 + (size_t)row * 512 + (t - 1) * 256 + e) = u;
    }
}

// ---------------------------------------------------------------------------
// K1: GRU step + profile encoding.  64 blocks x 256 threads.
// ---------------------------------------------------------------------------
__global__ __launch_bounds__(256) void k_gru(
    const float* __restrict__ tables, const float* __restrict__ Wih,
    const float* __restrict__ Whh, const float* __restrict__ bih,
    const float* __restrict__ bhh, const float* __restrict__ Wp,
    const float* __restrict__ bp, const int* __restrict__ y,
    const float* __restrict__ h_, const float* __restrict__ pe,
    float* __restrict__ q0, float* __restrict__ enc, float* __restrict__ outh)
{
    int b = blockIdx.x, t = threadIdx.x;
    __shared__ float m_s[E_], h_s[E_], pe_s[PL_];
    int yb = y[b];
    m_s[t] = tables[(size_t)NW_ * E_ + (size_t)yb * E_ + t];  // row 0 is zero
    h_s[t] = h_[b * E_ + t];
    if (t < PL_) pe_s[t] = pe[b * PL_ + t];
    __syncthreads();

    float g_i[3], g_h[3];
#pragma unroll
    for (int g = 0; g < 3; g++) {
        int j = g * E_ + t;
        float ai = bih[j], ah = bhh[j];
        const float4* wi = (const float4*)(Wih + (size_t)j * E_);
        const float4* wh = (const float4*)(Whh + (size_t)j * E_);
#pragma unroll 8
        for (int e = 0; e < E_ / 4; e++) {
            float4 a = wi[e], c = wh[e];
            ai += a.x * m_s[4 * e] + a.y * m_s[4 * e + 1] +
                  a.z * m_s[4 * e + 2] + a.w * m_s[4 * e + 3];
            ah += c.x * h_s[4 * e] + c.y * h_s[4 * e + 1] +
                  c.z * h_s[4 * e + 2] + c.w * h_s[4 * e + 3];
        }
        g_i[g] = ai; g_h[g] = ah;
    }
    float r = 1.f / (1.f + expf(-(g_i[0] + g_h[0])));
    float z = 1.f / (1.f + expf(-(g_i[1] + g_h[1])));
    float n = tanhf(g_i[2] + r * g_h[2]);
    float hv = (1.f - z) * n + z * h_s[t];
    q0[b * E_ + t] = hv;
    outh[b * E_ + t] = hv;

    float ea = bp[t];
    const float4* wp = (const float4*)(Wp + (size_t)t * PL_);
#pragma unroll 8
    for (int p = 0; p < PL_ / 4; p++) {
        float4 a = wp[p];
        ea += a.x * pe_s[4 * p] + a.y * pe_s[4 * p + 1] +
              a.z * pe_s[4 * p + 2] + a.w * pe_s[4 * p + 3];
    }
    enc[b * E_ + t] = ea;
}

// ---------------------------------------------------------------------------
// K2: hop-0 scores from bf16 table t0b.  grid (32,64) x 256.
// Wave: 8 m; half-wave (32 lanes x 16B) covers one 512B row; one instr
// fetches two rows (f pair).  Full-wave shfl reduce sums e and f.
// ---------------------------------------------------------------------------
__global__ __launch_bounds__(256) void k_scores0(
    const u16* __restrict__ t0b, const int* __restrict__ ctx,
    const float* __restrict__ q, float* __restrict__ p_ws)
{
    int b = blockIdx.y, grp = blockIdx.x;
    int lane = threadIdx.x & 63, w = threadIdx.x >> 6;
    int h = lane >> 5, l32 = lane & 31, e0 = l32 * 8;
    float4 qa = *(const float4*)(q + b * E_ + e0);
    float4 qb = *(const float4*)(q + b * E_ + e0 + 4);
    int mbase = grp * 32 + w * 8;
    const int4* cp = (const int4*)(ctx + ((size_t)b * M_ + mbase) * 4);
    int4 c[8];
#pragma unroll
    for (int i = 0; i < 8; i++) c[i] = cp[i];

    float pa[8];
#pragma unroll
    for (int i = 0; i < 8; i++) {
        int ia = h ? c[i].y : c[i].x;
        int ib = h ? c[i].w : c[i].z;
        uint4 ra = *(const uint4*)(t0b + (size_t)ia * E_ + e0);
        uint4 rb = *(const uint4*)(t0b + (size_t)ib * E_ + e0);
        pa[i] = dot8(ra, qa, qb) + dot8(rb, qa, qb);
    }
#pragma unroll
    for (int o = 32; o > 0; o >>= 1)
#pragma unroll
        for (int i = 0; i < 8; i++) pa[i] += __shfl_xor(pa[i], o, 64);
    if (lane == 0)
#pragma unroll
        for (int i = 0; i < 8; i++) p_ws[(size_t)b * M_ + mbase + i] = pa[i];
}

// ---------------------------------------------------------------------------
// K3: softmax over m (in-place in p_ws) + qnext = qcur.  64 blocks x 256.
// ---------------------------------------------------------------------------
__global__ __launch_bounds__(256) void k_soft(
    float* __restrict__ p_ws, const float* __restrict__ qcur,
    float* __restrict__ qnext)
{
    int b = blockIdx.x, t = threadIdx.x;
    __shared__ float red[256];
    float4 v = *(const float4*)(p_ws + (size_t)b * M_ + t * 4);
    float lm = fmaxf(fmaxf(v.x, v.y), fmaxf(v.z, v.w));
    red[t] = lm;
    __syncthreads();
    for (int s = 128; s > 0; s >>= 1) {
        if (t < s) red[t] = fmaxf(red[t], red[t + s]);
        __syncthreads();
    }
    float mx = red[0];
    __syncthreads();
    float e0 = expf(v.x - mx), e1 = expf(v.y - mx);
    float e2 = expf(v.z - mx), e3 = expf(v.w - mx);
    red[t] = e0 + e1 + e2 + e3;
    __syncthreads();
    for (int s = 128; s > 0; s >>= 1) {
        if (t < s) red[t] += red[t + s];
        __syncthreads();
    }
    float inv = 1.f / red[0];
    float4 o = make_float4(e0 * inv, e1 * inv, e2 * inv, e3 * inv);
    *(float4*)(p_ws + (size_t)b * M_ + t * 4) = o;
    qnext[b * E_ + t] = qcur[b * E_ + t];
}

// ---------------------------------------------------------------------------
// K4: build mems1/mems2 (bf16) from interleaved t12, fused with o0 accum.
// grid (32,64) x 256.  Wave: 8 m; half h -> table 1+h; one instr per idx
// fetches 1KB covering both tables.  o0 = sum attn0[m]*mems1row (h==0).
// ---------------------------------------------------------------------------
__global__ __launch_bounds__(256) void k_mems12(
    const u16* __restrict__ t12, const int* __restrict__ ctx,
    const float* __restrict__ attn0, u16* __restrict__ mems1,
    u16* __restrict__ mems2, float* __restrict__ q1)
{
    int b = blockIdx.y, grp = blockIdx.x;
    int lane = threadIdx.x & 63, w = threadIdx.x >> 6;
    int h = lane >> 5, l32 = lane & 31, e0 = l32 * 8;
    int mbase = grp * 32 + w * 8;
    const int4* cp = (const int4*)(ctx + ((size_t)b * M_ + mbase) * 4);
    int4 c[8];
#pragma unroll
    for (int i = 0; i < 8; i++) c[i] = cp[i];
    float4 a01 = *(const float4*)(attn0 + (size_t)b * M_ + mbase);
    float4 a23 = *(const float4*)(attn0 + (size_t)b * M_ + mbase + 4);
    float wg[8] = {a01.x, a01.y, a01.z, a01.w, a23.x, a23.y, a23.z, a23.w};

    u16* mout = h ? mems2 : mems1;
    float o_acc[8] = {0, 0, 0, 0, 0, 0, 0, 0};
#pragma unroll
    for (int i = 0; i < 8; i++) {
        size_t off = (size_t)h * 256 + e0;
        uint4 r0 = *(const uint4*)(t12 + (size_t)c[i].x * 512 + off);
        uint4 r1 = *(const uint4*)(t12 + (size_t)c[i].y * 512 + off);
        uint4 r2 = *(const uint4*)(t12 + (size_t)c[i].z * 512 + off);
        uint4 r3 = *(const uint4*)(t12 + (size_t)c[i].w * 512 + off);
        float acc[8] = {0, 0, 0, 0, 0, 0, 0, 0};
        acc8(r0, acc); acc8(r1, acc); acc8(r2, acc); acc8(r3, acc);
        *(uint4*)(mout + ((size_t)(b * M_ + mbase + i)) * 256 + e0) = pack8(acc);
        if (h == 0) {
            float wgt = wg[i];
#pragma unroll
            for (int j = 0; j < 8; j++) o_acc[j] += wgt * acc[j];
        }
    }
    __shared__ float red[4][E_];
    if (h == 0)
#pragma unroll
        for (int j = 0; j < 8; j++) red[w][e0 + j] = o_acc[j];
    __syncthreads();
    int t = threadIdx.x;
    float s = red[0][t] + red[1][t] + red[2][t] + red[3][t];
    atomicAdd(q1 + b * E_ + t, s);
}

// ---------------------------------------------------------------------------
// K5: streaming scores over materialized mems (bf16).
// MODE 1: also p_resto -> out.  MODE 2: p -> out only.
// grid (32,64) x 256.  Wave: 8 m as 4 pair-instrs (half-wave per row).
// ---------------------------------------------------------------------------
template <int MODE>
__global__ __launch_bounds__(256) void k_sscores(
    const u16* __restrict__ mems, const float* __restrict__ q,
    const float* __restrict__ enc, float* __restrict__ p_ws,
    float* __restrict__ out)
{
    int b = blockIdx.y, grp = blockIdx.x;
    int lane = threadIdx.x & 63, w = threadIdx.x >> 6;
    int h = lane >> 5, l32 = lane & 31, e0 = l32 * 8;
    float4 qa = *(const float4*)(q + b * E_ + e0);
    float4 qb = *(const float4*)(q + b * E_ + e0 + 4);
    float4 ea4 = make_float4(0, 0, 0, 0), eb4 = make_float4(0, 0, 0, 0);
    if (MODE == 1) {
        float4 ev = *(const float4*)(enc + b * E_ + e0);
        float4 ew = *(const float4*)(enc + b * E_ + e0 + 4);
        ea4 = make_float4(qa.x * ev.x, qa.y * ev.y, qa.z * ev.z, qa.w * ev.w);
        eb4 = make_float4(qb.x * ew.x, qb.y * ew.y, qb.z * ew.z, qb.w * ew.w);
    }
    int mbase = grp * 32 + w * 8;
    float pa[4], pr[4];
#pragma unroll
    for (int i = 0; i < 4; i++) {
        int m = mbase + 2 * i + h;
        uint4 r = *(const uint4*)(mems + ((size_t)(b * M_ + m)) * 256 + e0);
        pa[i] = dot8(r, qa, qb);
        if (MODE == 1) pr[i] = dot8(r, ea4, eb4);
    }
#pragma unroll
    for (int o = 16; o > 0; o >>= 1)
#pragma unroll
        for (int i = 0; i < 4; i++) {
            pa[i] += __shfl_xor(pa[i], o, 64);
            if (MODE == 1) pr[i] += __shfl_xor(pr[i], o, 64);
        }
    if (l32 == 0) {
#pragma unroll
        for (int i = 0; i < 4; i++) {
            int m = mbase + 2 * i + h;
            if (MODE == 2) out[P_OFF + (size_t)b * M_ + m] = pa[i];
            else           p_ws[(size_t)b * M_ + m] = pa[i];
            if (MODE == 1) out[PR_OFF + (size_t)b * M_ + m] = pr[i];
        }
    }
}

// ---------------------------------------------------------------------------
// K6: streaming o = sum_m attn[m]*mems[m,:] -> atomic into qnext.
// grid (8,64) x 256: block does 128 m; half-wave per row.
// ---------------------------------------------------------------------------
__global__ __launch_bounds__(256) void k_so(
    const u16* __restrict__ mems, const float* __restrict__ attn,
    float* __restrict__ qnext)
{
    int b = blockIdx.y, ch = blockIdx.x;
    int lane = threadIdx.x & 63, w = threadIdx.x >> 6;
    int h = lane >> 5, l32 = lane & 31, e0 = l32 * 8;
    int m0 = ch * 128;
    float acc[8] = {0, 0, 0, 0, 0, 0, 0, 0};
    for (int i = 0; i < 16; i++) {
        int m = m0 + i * 8 + w * 2 + h;
        float wgt = attn[(size_t)b * M_ + m];
        uint4 r = *(const uint4*)(mems + ((size_t)(b * M_ + m)) * 256 + e0);
        acc[0] += wgt * bflo(r.x); acc[1] += wgt * bfhi(r.x);
        acc[2] += wgt * bflo(r.y); acc[3] += wgt * bfhi(r.y);
        acc[4] += wgt * bflo(r.z); acc[5] += wgt * bfhi(r.z);
        acc[6] += wgt * bflo(r.w); acc[7] += wgt * bfhi(r.w);
    }
    __shared__ float red[8][E_];
    int hw = threadIdx.x >> 5;
#pragma unroll
    for (int j = 0; j < 8; j++) red[hw][e0 + j] = acc[j];
    __syncthreads();
    int t = threadIdx.x;
    float s = 0.f;
#pragma unroll
    for (int k = 0; k < 8; k++) s += red[k][t];
    atomicAdd(qnext + b * E_ + t, s);
}

// ---------------------------------------------------------------------------
// K7: p_vocab = [h ; o0] @ Wv^T + bv via MFMA 16x16x32 bf16.
// ---------------------------------------------------------------------------
__global__ __launch_bounds__(256) void k_pvocab(
    const float* __restrict__ Wv, const float* __restrict__ bv,
    const float* __restrict__ q0, const float* __restrict__ q1,
    float* __restrict__ out)
{
    __shared__ u16 X[64 * 512];  // 64KB
    int t = threadIdx.x;
#pragma unroll
    for (int it = 0; it < 16; it++) {
        int id = t + it * 256;
        int bb = id >> 6, c = id & 63;
        float v[8];
        if (c < 32) {
            const float* s = q0 + bb * E_ + c * 8;
#pragma unroll
            for (int j = 0; j < 8; j++) v[j] = s[j];
        } else {
            const float* s1 = q1 + bb * E_ + (c - 32) * 8;
            const float* s0 = q0 + bb * E_ + (c - 32) * 8;
#pragma unroll
            for (int j = 0; j < 8; j++) v[j] = s1[j] - s0[j];
        }
        uint4 uv = pack8(v);
        *(uint4*)(&X[bb * 512 + ((c ^ (bb & 7)) << 3)]) = uv;
    }
    __syncthreads();

    int lane = t & 63, w = t >> 6;
    int n0 = blockIdx.x * 128 + w * 32;
    int l15 = lane & 15, quad = lane >> 4;
    f32x4 acc[4][2];
#pragma unroll
    for (int mt = 0; mt < 4; mt++)
#pragma unroll
        for (int nt = 0; nt < 2; nt++)
            acc[mt][nt] = f32x4{0.f, 0.f, 0.f, 0.f};

    for (int ks = 0; ks < 16; ks++) {
        bf16x8 a[4], bfr[2];
#pragma unroll
        for (int mt = 0; mt < 4; mt++) {
            int m = mt * 16 + l15;
            int c = ks * 4 + quad;
            a[mt] = *(const bf16x8*)(&X[m * 512 + ((c ^ (m & 7)) << 3)]);
        }
#pragma unroll
        for (int nt = 0; nt < 2; nt++) {
            int n = n0 + nt * 16 + l15;
            const float4* wp = (const float4*)(Wv + (size_t)n * 512 + ks * 32 + quad * 8);
            bfr[nt] = pack_bf8(wp[0], wp[1]);
        }
#pragma unroll
        for (int mt = 0; mt < 4; mt++)
#pragma unroll
            for (int nt = 0; nt < 2; nt++)
                acc[mt][nt] = __builtin_amdgcn_mfma_f32_16x16x32_bf16(
                    a[mt], bfr[nt], acc[mt][nt], 0, 0, 0);
    }
#pragma unroll
    for (int nt = 0; nt < 2; nt++) {
        int n = n0 + nt * 16 + l15;
        float bvv = bv[n];
#pragma unroll
        for (int mt = 0; mt < 4; mt++) {
#pragma unroll
            for (int j = 0; j < 4; j++) {
                int m = mt * 16 + quad * 4 + j;
                out[PV_OFF + (size_t)m * 32000 + n] = acc[mt][nt][j] + bvv;
            }
        }
    }
}

// ---------------------------------------------------------------------------
extern "C" void kernel_launch(void* const* d_in, const int* in_sizes, int n_in,
                              void* d_out, int out_size, void* d_ws, size_t ws_size,
                              hipStream_t stream)
{
    const float* tables = (const float*)d_in[0];
    const float* Wih = (const float*)d_in[1];
    const float* Whh = (const float*)d_in[2];
    const float* bih = (const float*)d_in[3];
    const float* bhh = (const float*)d_in[4];
    const float* Wp  = (const float*)d_in[5];
    const float* bp  = (const float*)d_in[6];
    const float* Wv  = (const float*)d_in[7];
    const float* bv  = (const float*)d_in[8];
    const int* ctx = (const int*)d_in[9];
    const int* y   = (const int*)d_in[10];
    const float* h_  = (const float*)d_in[11];
    const float* pe  = (const float*)d_in[12];
    float* out = (float*)d_out;

    // ws layout
    float* Wf   = (float*)d_ws;
    float* q    = Wf;            // q0/q1/q2 at 0/16384/32768
    float* enc  = Wf + 65536;
    float* p_ws = Wf + 81920;    // scores then attn in-place (65536 floats)
    char* base  = (char*)d_ws + 589824;           // 16-aligned
    u16* t0b    = (u16*)base;                      // 32000*256
    u16* t12    = (u16*)(base + 16384000);         // 32000*512
    u16* mems1  = (u16*)(base + 16384000 + 32768000);
    u16* mems2  = (u16*)(base + 16384000 + 32768000 + 33554432);

    k_conv<<<dim3(4000, 3), 256, 0, stream>>>(tables, t0b, t12);
    k_gru<<<64, 256, 0, stream>>>(tables, Wih, Whh, bih, bhh, Wp, bp, y, h_, pe,
                                  q, enc, out + H_OFF);
    // hop 0 scores (random gather on bf16 table 0)
    k_scores0<<<dim3(32, 64), 256, 0, stream>>>(t0b, ctx, q, p_ws);
    k_soft<<<64, 256, 0, stream>>>(p_ws, q, q + 16384);
    // build mems1/mems2 + fused o0 -> q1
    k_mems12<<<dim3(32, 64), 256, 0, stream>>>(t12, ctx, p_ws, mems1, mems2,
                                               q + 16384);
    // hop 1: stream mems1 (+ p_resto)
    k_sscores<1><<<dim3(32, 64), 256, 0, stream>>>(mems1, q + 16384, enc, p_ws, out);
    k_soft<<<64, 256, 0, stream>>>(p_ws, q + 16384, q + 32768);
    // o1: stream mems2 -> q2
    k_so<<<dim3(8, 64), 256, 0, stream>>>(mems2, p_ws, q + 32768);
    // hop 2: stream mems2 -> p out
    k_sscores<2><<<dim3(32, 64), 256, 0, stream>>>(mems2, q + 32768, enc, p_ws, out);
    // p_vocab head
    k_pvocab<<<250, 256, 0, stream>>>(Wv, bv, q, q + 16384, out);
}